// Round 1
// baseline (351.807 us; speedup 1.0000x reference)
//
#include <hip/hip_runtime.h>

// B is fixed at 64 == wavefront size for this problem; the whole layout
// strategy (lane = batch index) depends on it.

__global__ void prep_kernel(const float* __restrict__ x, float* __restrict__ xT,
                            float* __restrict__ acc, int N) {
    // Transpose x [64, N] -> xT [N, 64] via LDS tile, and zero acc [N, 64].
    __shared__ float tile[64][65];  // +1 pad: conflict-free transposed reads
    int n0 = blockIdx.x * 64;
    int tid = threadIdx.x;
    // load: n fastest -> coalesced reads of x rows
    for (int lin = tid; lin < 64 * 64; lin += 256) {
        int nl = lin & 63, b = lin >> 6;
        int n = n0 + nl;
        tile[b][nl] = (n < N) ? x[(long)b * N + n] : 0.f;
    }
    __syncthreads();
    // store: b fastest -> coalesced writes of xT rows; zero acc in same pass
    for (int lin = tid; lin < 64 * 64; lin += 256) {
        int b = lin & 63, nl = lin >> 6;
        int n = n0 + nl;
        if (n < N) {
            xT[(long)n * 64 + b] = tile[b][nl];
            acc[(long)n * 64 + b] = 0.f;
        }
    }
}

__global__ void edge_kernel(const float* __restrict__ adj, const float* __restrict__ w,
                            const int* __restrict__ src, const int* __restrict__ dst,
                            const float* __restrict__ xT, float* __restrict__ acc,
                            int E) {
    // One wave handles a tile of 64 edges; lane = batch index.
    int lane = threadIdx.x & 63;
    int gwave = (int)((blockIdx.x * blockDim.x + threadIdx.x) >> 6);
    int base = gwave << 6;
    if (base >= E) return;
    // Mark base wave-uniform so edge-scalar loads go to the scalar pipe.
    base = __builtin_amdgcn_readfirstlane(base);
    int cnt = E - base;
    if (cnt > 64) cnt = 64;
#pragma unroll 4
    for (int j = 0; j < cnt; ++j) {
        int e = base + j;
        float cj = adj[e] * w[e];   // wave-uniform
        int sj = src[e];            // wave-uniform
        int dj = dst[e];            // wave-uniform
        // coalesced 256B gather of source node's batch column
        float v = cj * xT[sj * 64 + lane];
        // coalesced 256B atomic scatter to destination node's batch column
        atomicAdd(&acc[dj * 64 + lane], v);
    }
}

__global__ void finish_kernel(const float* __restrict__ acc, const float* __restrict__ x,
                              const float* __restrict__ self_w, const float* __restrict__ bias,
                              float* __restrict__ out, int N) {
    int n = blockIdx.x * blockDim.x + threadIdx.x;
    int b = blockIdx.y;
    if (n >= N) return;
    float sl = x[n] * self_w[n];            // self-loop uses x[0] row only (ref quirk)
    float v = acc[(long)n * 64 + b] * sl + bias[n];
    out[(long)b * N + n] = fmaxf(v, 0.f);   // coalesced over n
}

extern "C" void kernel_launch(void* const* d_in, const int* in_sizes, int n_in,
                              void* d_out, int out_size, void* d_ws, size_t ws_size,
                              hipStream_t stream) {
    const float* x      = (const float*)d_in[0];
    const float* adj    = (const float*)d_in[1];
    const float* w      = (const float*)d_in[2];
    const float* self_w = (const float*)d_in[3];
    const float* bias   = (const float*)d_in[4];
    const int*   src    = (const int*)d_in[5];
    const int*   dst    = (const int*)d_in[6];

    int N = in_sizes[3];            // 20000
    int E = in_sizes[1];            // 1,280,000
    int B = in_sizes[0] / N;        // 64 (== wave size; layout assumes this)
    (void)B; (void)n_in; (void)ws_size;

    float* xT  = (float*)d_ws;                  // N*64 floats
    float* acc = xT + (size_t)N * 64;           // N*64 floats
    float* out = (float*)d_out;

    int nb_prep = (N + 63) / 64;
    hipLaunchKernelGGL(prep_kernel, dim3(nb_prep), dim3(256), 0, stream, x, xT, acc, N);

    int waves = (E + 63) / 64;                  // 20000
    int nb_edge = (waves + 3) / 4;              // 5000 blocks of 4 waves
    hipLaunchKernelGGL(edge_kernel, dim3(nb_edge), dim3(256), 0, stream,
                       adj, w, src, dst, xT, acc, E);

    dim3 gf((N + 255) / 256, 64);
    hipLaunchKernelGGL(finish_kernel, gf, dim3(256), 0, stream, acc, x, self_w, bias, out, N);
}